// Round 19
// baseline (5044.360 us; speedup 1.0000x reference)
//
#include <hip/hip_runtime.h>
#include <hip/hip_bf16.h>
#include <stdint.h>

// BayesGRU eval: T=512, B=64, D_IN=1024, D_H=1024.
// Round 19 = R18 champion (4.87ms) + fp8(e4m3) h-transport for GATE h-parts
// (deep path only; shallow = verbatim R18 bf16):
//   c-WGs publish h additionally as e4m3 into hA8 (frag-linear byte slab,
//   ring, same ack chain as hA16). Both classes' gate h-MFMAs use
//   mfma_f32_16x16x32_fp8_fp8 with weights pre-scaled x64 into e4m3 (W8);
//   result * 1/64. Gate path feeds sigmoid (slope<=1/4) -> error-attenuated.
//   rh (cell operand, tanh-sensitive) stays bf16. r-WGs' own-col h scalars
//   stay bf16 (hA16). Critical r-class h-burst halves: 16KB -> 8KB per wave.
// Everything else verbatim R18 (proven): frag-linear fidx; WT(sc0sc1) stores
// + bypass(sc0sc1) loads for same-dispatch data; flags 64B lines, leader
// polls, H=fam0 q8 / R=fam1 q8; out stores after H-post.

#define T_STEPS 512
#define BATCH   64
#define DIN     1024
#define DH      1024
#define NWG     128
#define SLAB    65536            // B*DH elements

typedef __attribute__((ext_vector_type(8))) short bf16x8;
typedef __attribute__((ext_vector_type(4))) float f32x4;
typedef __attribute__((ext_vector_type(2))) int i32x2;

static __device__ __forceinline__ unsigned short f2bf(float x) {
    union { float f; uint32_t u; } v; v.f = x;
    uint32_t u = v.u;
    return (unsigned short)((u + 0x7FFFu + ((u >> 16) & 1u)) >> 16);
}
static __device__ __forceinline__ float bf2f(unsigned short u) {
    union { uint32_t v; float f; } x; x.v = (uint32_t)u << 16; return x.f;
}
// OCP e4m3fn encode, RNE, denormals handled (step 2^-9), clamp to 448
static __device__ __forceinline__ unsigned char f2e4m3(float x) {
    union { float f; uint32_t u; } v; v.f = x;
    unsigned char s = (unsigned char)((v.u >> 24) & 0x80);
    float ax = fabsf(x);
    if (ax >= 448.f) return (unsigned char)(s | 0x7e);
    if (ax < 0.015625f) {                    // denormal region
        int m = (int)(ax * 512.f + 0.5f);    // 0..8 (8 -> 0x08 == 2^-6)
        return (unsigned char)(s | (unsigned char)m);
    }
    uint32_t u = v.u;
    u += 0x7FFFFu + ((u >> 20) & 1u);        // RNE to 3 mantissa bits
    int exp = (int)((u >> 23) & 0xff) - 127; // [-6, 8]
    uint32_t mant = (u >> 20) & 7u;
    return (unsigned char)(s | (unsigned char)(((exp + 7) << 3) | mant));
}
static __device__ __forceinline__ bf16x8 cvt8(float4 a, float4 b) {
    union { bf16x8 v; unsigned d[4]; } u;
    asm("v_cvt_pk_bf16_f32 %0, %1, %2" : "=v"(u.d[0]) : "v"(a.x), "v"(a.y));
    asm("v_cvt_pk_bf16_f32 %0, %1, %2" : "=v"(u.d[1]) : "v"(a.z), "v"(a.w));
    asm("v_cvt_pk_bf16_f32 %0, %1, %2" : "=v"(u.d[2]) : "v"(b.x), "v"(b.y));
    asm("v_cvt_pk_bf16_f32 %0, %1, %2" : "=v"(u.d[3]) : "v"(b.z), "v"(b.w));
    return u.v;
}

// fragment-linear index for bf16 dynamic operands (hA16, rh)
static __device__ __forceinline__ int fidx(int row, int k) {
    return ((((row >> 4) * 32 + (k >> 5)) * 64) + (((k >> 3) & 3) * 16) + (row & 15)) * 8
           + (k & 7);
}
// fragment-linear BYTE index for fp8 h slab
static __device__ __forceinline__ int f8idx(int row, int k) {
    return ((row >> 4) * 32 + (k >> 5)) * 512 + ((k >> 3) & 3) * 128 + (row & 15) * 8
           + (k & 7);
}

// ---- stale-immune transport: WT stores + LLC-bypass loads (proven R3-R18) --
static __device__ __forceinline__ void st_wt_u16(void* p, unsigned v) {
    asm volatile("global_store_short %0, %1, off sc0 sc1" :: "v"(p), "v"(v) : "memory");
}
static __device__ __forceinline__ void st_wt_u8(void* p, unsigned v) {
    asm volatile("global_store_byte %0, %1, off sc0 sc1" :: "v"(p), "v"(v) : "memory");
}
static __device__ __forceinline__ bf16x8 ld_llc(const unsigned short* p) {
    bf16x8 r;
    asm volatile("global_load_dwordx4 %0, %1, off sc0 sc1" : "=v"(r) : "v"(p));
    return r;
}
static __device__ __forceinline__ long ld_llc8(const unsigned char* p) {
    i32x2 r;
    asm volatile("global_load_dwordx2 %0, %1, off sc0 sc1" : "=v"(r) : "v"(p));
    union { i32x2 v; long l; } u; u.v = r; return u.l;
}
static __device__ __forceinline__ unsigned ld_llc_u16(const unsigned short* p) {
    unsigned r;
    asm volatile("global_load_ushort %0, %1, off sc0 sc1" : "=v"(r) : "v"(p));
    return r;
}
static __device__ __forceinline__ void vwait0() {
    asm volatile("s_waitcnt vmcnt(0)" ::: "memory");
    __builtin_amdgcn_sched_barrier(0);   // rule #18
}

// ---- flag wait/post (verbatim R18) -----------------------------------------
static __device__ __forceinline__ void wait_fam(const int* cnt, int t, int fam, int quota) {
    const int* b = cnt + t * 128 + fam;
    for (;;) {
        int a0,a1,a2,a3,a4,a5,a6,a7;
        asm volatile("global_load_dword %0, %1, off sc0 sc1" : "=v"(a0) : "v"(b));
        asm volatile("global_load_dword %0, %1, off sc0 sc1" : "=v"(a1) : "v"(b+16));
        asm volatile("global_load_dword %0, %1, off sc0 sc1" : "=v"(a2) : "v"(b+32));
        asm volatile("global_load_dword %0, %1, off sc0 sc1" : "=v"(a3) : "v"(b+48));
        asm volatile("global_load_dword %0, %1, off sc0 sc1" : "=v"(a4) : "v"(b+64));
        asm volatile("global_load_dword %0, %1, off sc0 sc1" : "=v"(a5) : "v"(b+80));
        asm volatile("global_load_dword %0, %1, off sc0 sc1" : "=v"(a6) : "v"(b+96));
        asm volatile("global_load_dword %0, %1, off sc0 sc1" : "=v"(a7) : "v"(b+112));
        asm volatile("s_waitcnt vmcnt(0)" ::: "memory");
        __builtin_amdgcn_sched_barrier(0);
        if (a0>=quota && a1>=quota && a2>=quota && a3>=quota &&
            a4>=quota && a5>=quota && a6>=quota && a7>=quota) break;
        __builtin_amdgcn_s_sleep(1);
    }
}
static __device__ __forceinline__ void wg_wait(const int* cnt, int t, int fam, int quota) {
    if (threadIdx.x == 0) wait_fam(cnt, t, fam, quota);
    __syncthreads();
}
static __device__ __forceinline__ void post_fam(int* cnt, int t, int g, int fam) {
    __hip_atomic_fetch_add(cnt + t * 128 + g * 16 + fam, 1,
                           __ATOMIC_RELAXED, __HIP_MEMORY_SCOPE_AGENT);
}

// ---------------- weight packing (R18 + fp8 gate h-part W8) -----------------
// Wur: [kk=64][b=128][kg=4][col=16][8] bf16 (u cols b<64, r cols b>=64)
// Wc : [kk=64][b=64 ][kg=4][col=16][8] bf16
// W8 : [kk8=32][b=128][kg=4][col=16][8] e4m3 of (w*64), h-part only (deep)
__global__ __launch_bounds__(256) void gru_pack_weights(
    const float* __restrict__ wihu, const float* __restrict__ wihr,
    const float* __restrict__ wihc, const float* __restrict__ whhu,
    const float* __restrict__ whhr, const float* __restrict__ whhc,
    unsigned short* __restrict__ Wur, unsigned short* __restrict__ Wc,
    unsigned char* __restrict__ W8, int deep)
{
    const int total = 3072 * 2048;
    for (int idx = blockIdx.x * 256 + threadIdx.x; idx < total; idx += gridDim.x * 256) {
        int n = idx >> 11;
        int k = idx & 2047;
        int j = n & 1023;
        float v;
        if (n < 1024)      v = (k < DIN) ? wihu[j*DIN + k] : whhu[j*DH + (k - DIN)];
        else if (n < 2048) v = (k < DIN) ? wihr[j*DIN + k] : whhr[j*DH + (k - DIN)];
        else               v = (k < DIN) ? wihc[j*DIN + k] : whhc[j*DH + (k - DIN)];
        unsigned short bv = f2bf(v);
        int kk = k >> 5, kg = (k >> 3) & 3, r = k & 7;
        if (n < 2048) {
            int b = n >> 4, col = n & 15;
            Wur[((((size_t)kk*128 + b)*4 + kg)*16 + col)*8 + r] = bv;
            if (deep && k >= DIN) {
                int kk8 = kk - 32;
                W8[(((size_t)kk8*128 + b)*512) + kg*128 + col*8 + r] = f2e4m3(v * 64.f);
            }
        } else {
            int nc = n - 2048, b = nc >> 4, col = nc & 15;
            Wc [((((size_t)kk*64 + b)*4 + kg)*16 + col)*8 + r] = bv;
        }
    }
}

// ---------------- emb fp32 -> bf16 (deep path) ------------------------------
__global__ __launch_bounds__(256) void gru_convert_x(
    const float* __restrict__ emb, unsigned short* __restrict__ xbf)
{
    size_t i = (size_t)blockIdx.x * 256 + threadIdx.x;
    float4 v = ((const float4*)emb)[i];
    ushort4 b;
    b.x = f2bf(v.x); b.y = f2bf(v.y); b.z = f2bf(v.z); b.w = f2bf(v.w);
    ((ushort4*)xbf)[i] = b;
}

// ---------------- init: hA16[0], hA8[0], counters = 0 -----------------------
__global__ __launch_bounds__(256) void gru_init(
    const float* __restrict__ hx, unsigned short* __restrict__ hA,
    unsigned char* __restrict__ hA8, int* __restrict__ cnt)
{
    int i = blockIdx.x * 256 + threadIdx.x;   // 256x256 = 65536
    int row = i >> 10, k = i & 1023;
    hA[fidx(row, k)] = f2bf(hx[i]);
    hA8[f8idx(row, k)] = f2e4m3(hx[i]);
    cnt[i] = 0;
}

// ---------------- persistent GRU kernel -------------------------------------
// c-WG (wg<64): u-gate + cell + h-update for cols [16wg,16wg+16).
// r-WG (wg>=64): r-gate for cols [16(wg-64),...); publishes rh.
__global__ __launch_bounds__(256, 1) void gru_persistent(
    const unsigned short* __restrict__ Wur, const unsigned short* __restrict__ Wc,
    const unsigned char* __restrict__ W8,
    const float* __restrict__ emb, const unsigned short* __restrict__ xbf,
    const float* __restrict__ hx,
    const float* __restrict__ bu, const float* __restrict__ br, const float* __restrict__ bc,
    unsigned short* __restrict__ hA, unsigned char* __restrict__ hA8,
    unsigned short* __restrict__ rh,
    float* __restrict__ out, int* __restrict__ cnt, int deep)
{
    __shared__ unsigned short wur_s[32768];   // 64 KB (deep uses kk0-31 only)
    __shared__ unsigned short wc_s [32768];   // 64 KB (c-WGs)
    __shared__ unsigned char  w8_s [16384];   // 16 KB fp8 gate h-part (deep)

    const int wg   = blockIdx.x;
    const int tid  = threadIdx.x;
    const int lane = tid & 63;
    const int wid  = tid >> 6;
    const int m0   = wid * 16;
    const int c15  = lane & 15;
    const int kg   = lane >> 4;

    if (deep) {
        for (int i = tid; i < 2048; i += 256) {          // x-part bf16, 32KB
            int kk = i >> 6, j = i & 63;
            ((uint4*)wur_s)[i] =
                *(const uint4*)((const char*)Wur + ((size_t)kk*128 + wg)*1024 + j*16);
        }
        for (int i = tid; i < 1024; i += 256) {          // fp8 h-part, 16KB
            int kk8 = i >> 5, j = i & 31;
            ((uint4*)w8_s)[i] =
                *(const uint4*)(W8 + ((size_t)kk8*128 + wg)*512 + j*16);
        }
    } else {
        for (int i = tid; i < 4096; i += 256) {
            int kk = i >> 6, j = i & 63;
            ((uint4*)wur_s)[i] =
                *(const uint4*)((const char*)Wur + ((size_t)kk*128 + wg)*1024 + j*16);
        }
    }
    if (wg < 64) {
        for (int i = tid; i < 4096; i += 256) {
            int kk = i >> 6, j = i & 63;
            ((uint4*)wc_s)[i] =
                *(const uint4*)((const char*)Wc + ((size_t)kk*64 + wg)*1024 + j*16);
        }
    }
    __syncthreads();

    const int v    = wg & 63;
    const int colj = v * 16 + c15;

    if (wg < 64) {
        // ================= c-path: u + cell + h-update =================
        const float bu_ = bu[colj], bc_ = bc[colj];
        float hreg[4];
        #pragma unroll
        for (int i = 0; i < 4; ++i) hreg[i] = hx[(m0 + kg*4 + i) * DH + colj];

        for (int t = 0; t < T_STEPS; ++t) {
            const int par = t & 1;
            f32x4 au = {0.f,0.f,0.f,0.f}, ac = {0.f,0.f,0.f,0.f};
            f32x4 au8 = {0.f,0.f,0.f,0.f};
            bf16x8 fr[32];

            // --- x-parts of u and c (cached; overlaps waiting time) ---
            if (deep) {
                const unsigned short* xp =
                    xbf + ((size_t)t * BATCH + (m0 + c15)) * DIN + kg * 8;
                #pragma unroll
                for (int kk = 0; kk < 32; ++kk) {
                    bf16x8 f = *(const bf16x8*)(xp + kk * 32);
                    au = __builtin_amdgcn_mfma_f32_16x16x32_bf16(
                             f, *(const bf16x8*)(wur_s + kk*512 + lane*8), au, 0, 0, 0);
                    ac = __builtin_amdgcn_mfma_f32_16x16x32_bf16(
                             f, *(const bf16x8*)(wc_s + kk*512 + lane*8), ac, 0, 0, 0);
                }
            } else {
                const float* xp = emb + ((size_t)t * BATCH + (m0 + c15)) * DIN + kg * 8;
                #pragma unroll
                for (int kk = 0; kk < 32; ++kk) {
                    float4 a = *(const float4*)(xp + kk * 32);
                    float4 b = *(const float4*)(xp + kk * 32 + 4);
                    bf16x8 f = cvt8(a, b);
                    au = __builtin_amdgcn_mfma_f32_16x16x32_bf16(
                             f, *(const bf16x8*)(wur_s + kk*512 + lane*8), au, 0, 0, 0);
                    ac = __builtin_amdgcn_mfma_f32_16x16x32_bf16(
                             f, *(const bf16x8*)(wc_s + kk*512 + lane*8), ac, 0, 0, 0);
                }
            }

            // --- h-part of u ---
            if (t) wg_wait(cnt, t-1, 0, 8);
            if (deep) {
                const unsigned char* hb8 = hA8 + par * SLAB + wid * 16384;
                long fr8[32];
                #pragma unroll
                for (int kk = 0; kk < 32; ++kk) fr8[kk] = ld_llc8(hb8 + kk * 512 + lane * 8);
                vwait0();
                #pragma unroll
                for (int kk = 0; kk < 32; ++kk)
                    au8 = __builtin_amdgcn_mfma_f32_16x16x32_fp8_fp8(
                              fr8[kk], *(const long*)(w8_s + kk*512 + lane*8), au8, 0, 0, 0);
            } else {
                const unsigned short* hb = hA + par * SLAB + wid * 16384;
                #pragma unroll
                for (int kk = 0; kk < 32; ++kk) fr[kk] = ld_llc(hb + kk * 512 + lane * 8);
                vwait0();
                #pragma unroll
                for (int kk = 0; kk < 32; ++kk)
                    au = __builtin_amdgcn_mfma_f32_16x16x32_bf16(
                             fr[kk], *(const bf16x8*)(wur_s + (kk+32)*512 + lane*8),
                             au, 0, 0, 0);
            }

            // --- single R wait; issue full rh burst; sigmoid hides under it ---
            const unsigned short* rb = rh + wid * 16384;
            wg_wait(cnt, t, 1, 8);
            #pragma unroll
            for (int kk = 0; kk < 32; ++kk) fr[kk] = ld_llc(rb + kk * 512 + lane * 8);

            float ureg[4];
            #pragma unroll
            for (int i = 0; i < 4; ++i) {
                float pre = au[i] + au8[i] * 0.015625f + bu_;
                ureg[i] = 1.f / (1.f + __expf(-pre));
            }

            vwait0();
            #pragma unroll
            for (int kk = 0; kk < 32; ++kk)
                ac = __builtin_amdgcn_mfma_f32_16x16x32_bf16(
                         fr[kk], *(const bf16x8*)(wc_s + (kk+32)*512 + lane*8), ac, 0, 0, 0);

            // --- update, publish h (bf16 fidx + fp8 f8idx), post H; out after ---
            unsigned short* hnxt  = hA  + (par ^ 1) * SLAB;
            unsigned char*  hnxt8 = hA8 + (par ^ 1) * SLAB;
            float hnv[4];
            #pragma unroll
            for (int i = 0; i < 4; ++i) {
                int row = m0 + kg * 4 + i;
                float pre = ac[i] + bc_;
                float e   = __expf(2.f * pre);
                float cel = 1.f - 2.f / (e + 1.f);          // tanh
                float hn  = (1.f - ureg[i]) * hreg[i] + ureg[i] * cel;
                hreg[i] = hn;
                hnv[i]  = hn;
                st_wt_u16(hnxt + fidx(row, colj), (unsigned)f2bf(hn));
                if (deep) st_wt_u8(hnxt8 + f8idx(row, colj), (unsigned)f2e4m3(hn));
            }
            asm volatile("s_waitcnt vmcnt(0)" ::: "memory");
            __syncthreads();
            if (tid == 0) post_fam(cnt, t, wg >> 3, 0);

            float* out_t = out + (size_t)t * SLAB;          // write-only, off-path
            #pragma unroll
            for (int i = 0; i < 4; ++i) {
                int row = m0 + kg * 4 + i;
                out_t[row * DH + colj] = hnv[i];
                if (t == T_STEPS - 1)
                    out[(size_t)T_STEPS * SLAB + row * DH + colj] = hnv[i];
            }
        }
    } else {
        // ================= r-path: reset gate -> rh =================
        const float br_ = br[colj];
        for (int t = 0; t < T_STEPS; ++t) {
            const int par = t & 1;
            const unsigned short* ha = hA + par * SLAB;

            f32x4 ar = {0.f,0.f,0.f,0.f};
            f32x4 ar8 = {0.f,0.f,0.f,0.f};

            // --- x-part of r (cached; overlaps waiting time) ---
            if (deep) {
                const unsigned short* xp =
                    xbf + ((size_t)t * BATCH + (m0 + c15)) * DIN + kg * 8;
                #pragma unroll
                for (int kk = 0; kk < 32; ++kk)
                    ar = __builtin_amdgcn_mfma_f32_16x16x32_bf16(
                             *(const bf16x8*)(xp + kk * 32),
                             *(const bf16x8*)(wur_s + kk*512 + lane*8), ar, 0, 0, 0);
            } else {
                const float* xp = emb + ((size_t)t * BATCH + (m0 + c15)) * DIN + kg * 8;
                #pragma unroll
                for (int kk = 0; kk < 32; ++kk) {
                    float4 a = *(const float4*)(xp + kk * 32);
                    float4 b = *(const float4*)(xp + kk * 32 + 4);
                    ar = __builtin_amdgcn_mfma_f32_16x16x32_bf16(
                             cvt8(a, b), *(const bf16x8*)(wur_s + kk*512 + lane*8),
                             ar, 0, 0, 0);
                }
            }

            // --- h-part of r (+ own-col bf16 h scalars) ---
            if (t) wg_wait(cnt, t-1, 0, 8);
            unsigned hp16[4];
            #pragma unroll
            for (int i = 0; i < 4; ++i)
                hp16[i] = ld_llc_u16(ha + fidx(m0 + kg*4 + i, colj));
            if (deep) {
                const unsigned char* hb8 = hA8 + par * SLAB + wid * 16384;
                long fr8[32];
                #pragma unroll
                for (int kk = 0; kk < 32; ++kk) fr8[kk] = ld_llc8(hb8 + kk * 512 + lane * 8);
                vwait0();
                #pragma unroll
                for (int kk = 0; kk < 32; ++kk)
                    ar8 = __builtin_amdgcn_mfma_f32_16x16x32_fp8_fp8(
                              fr8[kk], *(const long*)(w8_s + kk*512 + lane*8), ar8, 0, 0, 0);
            } else {
                bf16x8 fr[32];
                const unsigned short* hb = ha + wid * 16384;
                #pragma unroll
                for (int kk = 0; kk < 32; ++kk) fr[kk] = ld_llc(hb + kk * 512 + lane * 8);
                vwait0();
                #pragma unroll
                for (int kk = 0; kk < 32; ++kk)
                    ar = __builtin_amdgcn_mfma_f32_16x16x32_bf16(
                             fr[kk], *(const bf16x8*)(wur_s + (kk+32)*512 + lane*8),
                             ar, 0, 0, 0);
            }

            // --- publish rh (bf16 frag-linear WT), post R ---
            #pragma unroll
            for (int i = 0; i < 4; ++i) {
                int row = m0 + kg * 4 + i;
                float pre = ar[i] + ar8[i] * 0.015625f + br_;
                float s = 1.f / (1.f + __expf(-pre));
                st_wt_u16(rh + fidx(row, colj),
                          (unsigned)f2bf(s * bf2f((unsigned short)hp16[i])));
            }
            asm volatile("s_waitcnt vmcnt(0)" ::: "memory");
            __syncthreads();
            if (tid == 0) post_fam(cnt, t, v >> 3, 1);
        }
    }
}

// ---------------- host launch ----------------------------------------------
extern "C" void kernel_launch(void* const* d_in, const int* in_sizes, int n_in,
                              void* d_out, int out_size, void* d_ws, size_t ws_size,
                              hipStream_t stream)
{
    const float* emb  = (const float*)d_in[0];
    const float* hx   = (const float*)d_in[1];
    const float* wihu = (const float*)d_in[2];
    const float* wihr = (const float*)d_in[3];
    const float* wihc = (const float*)d_in[4];
    const float* whhu = (const float*)d_in[5];
    const float* whhr = (const float*)d_in[6];
    const float* whhc = (const float*)d_in[7];
    const float* bu   = (const float*)d_in[8];
    const float* br   = (const float*)d_in[9];
    const float* bc   = (const float*)d_in[10];
    float* out = (float*)d_out;
    char*  ws  = (char*)d_ws;

    // ws layout (bytes):
    //   0          Wur   8 MiB
    //   8,388,608  Wc    4 MiB
    //   12,582,912 cnt   256 KiB flag lines
    //   12,845,056 hA16  256 KiB (2 slabs)
    //   13,107,200 rh    128 KiB
    //   13,238,272 hA8   128 KiB (2 fp8 slabs)   [<13.76MB proven region]
    //   13,369,344 W8    2 MiB  (deep only)
    //   16,777,216 xbf   64 MiB (deep only) -> deep need 83,886,080
    unsigned short* Wur = (unsigned short*)(ws + 0);
    unsigned short* Wc  = (unsigned short*)(ws + 8388608);
    int*            cnt = (int*)(ws + 12582912);
    unsigned short* hA  = (unsigned short*)(ws + 12845056);
    unsigned short* rhb = (unsigned short*)(ws + 13107200);
    unsigned char*  hA8 = (unsigned char*)(ws + 13238272);
    unsigned char*  W8  = (unsigned char*)(ws + 13369344);
    unsigned short* xbf = (unsigned short*)(ws + 16777216);
    const int deep = (ws_size >= 83886080ull) ? 1 : 0;

    gru_pack_weights<<<1024, 256, 0, stream>>>(wihu, wihr, wihc, whhu, whhr, whhc,
                                               Wur, Wc, W8, deep);
    if (deep) gru_convert_x<<<32768, 256, 0, stream>>>(emb, xbf);
    gru_init<<<256, 256, 0, stream>>>(hx, hA, hA8, cnt);
    gru_persistent<<<NWG, 256, 0, stream>>>(Wur, Wc, W8, emb, xbf, hx, bu, br, bc,
                                            hA, hA8, rhb, out, cnt, deep);
}

// Round 21
// 4870.327 us; speedup vs baseline: 1.0357x; 1.0357x over previous
//
#include <hip/hip_runtime.h>
#include <hip/hip_bf16.h>
#include <stdint.h>

// BayesGRU eval: T=512, B=64, D_IN=1024, D_H=1024.
// FINAL = Round 18 champion verbatim (4.87ms, passed + replay-revalidated).
// Persistent kernel, 128 WGs (1/CU), weights LDS-resident.
//   c-WGs (wg<64): u-gate + cell + h-update for 16 cols.
//   r-WGs (wg>=64): r-gate for 16 cols; publish rh.
// Transport (the only replay-safe scheme, est. R3-R18): same-dispatch
// cross-WG data = WT(sc0 sc1) stores + bypass(sc0 sc1) loads; read-only /
// prior-dispatch data (emb, xbf, packed weights) = normal cached loads.
// hA/rh in FRAGMENT-LINEAR layout (wave burst = contiguous 1KB/instr).
// Flags: 64B lines, leader-only polls, single R family.
//   H=fam0 q8 (c-WGs post g=wg>>3); R=fam1 q8 (r-WGs post g=v>>3).
// Out stores after H-post (off critical path).

#define T_STEPS 512
#define BATCH   64
#define DIN     1024
#define DH      1024
#define NWG     128
#define SLAB    65536            // B*DH elements (128KB bf16)

typedef __attribute__((ext_vector_type(8))) short bf16x8;
typedef __attribute__((ext_vector_type(4))) float f32x4;

static __device__ __forceinline__ unsigned short f2bf(float x) {
    union { float f; uint32_t u; } v; v.f = x;
    uint32_t u = v.u;
    return (unsigned short)((u + 0x7FFFu + ((u >> 16) & 1u)) >> 16);
}
static __device__ __forceinline__ float bf2f(unsigned short u) {
    union { uint32_t v; float f; } x; x.v = (uint32_t)u << 16; return x.f;
}
static __device__ __forceinline__ bf16x8 cvt8(float4 a, float4 b) {
    union { bf16x8 v; unsigned d[4]; } u;
    asm("v_cvt_pk_bf16_f32 %0, %1, %2" : "=v"(u.d[0]) : "v"(a.x), "v"(a.y));
    asm("v_cvt_pk_bf16_f32 %0, %1, %2" : "=v"(u.d[1]) : "v"(a.z), "v"(a.w));
    asm("v_cvt_pk_bf16_f32 %0, %1, %2" : "=v"(u.d[2]) : "v"(b.x), "v"(b.y));
    asm("v_cvt_pk_bf16_f32 %0, %1, %2" : "=v"(u.d[3]) : "v"(b.z), "v"(b.w));
    return u.v;
}

// fragment-linear index for the dynamic operands (hA, rh)
static __device__ __forceinline__ int fidx(int row, int k) {
    return ((((row >> 4) * 32 + (k >> 5)) * 64) + (((k >> 3) & 3) * 16) + (row & 15)) * 8
           + (k & 7);
}

// ---- stale-immune transport: WT stores + LLC-bypass loads (proven R3-R18) --
static __device__ __forceinline__ void st_wt_u16(void* p, unsigned v) {
    asm volatile("global_store_short %0, %1, off sc0 sc1" :: "v"(p), "v"(v) : "memory");
}
static __device__ __forceinline__ bf16x8 ld_llc(const unsigned short* p) {
    bf16x8 r;
    asm volatile("global_load_dwordx4 %0, %1, off sc0 sc1" : "=v"(r) : "v"(p));
    return r;
}
static __device__ __forceinline__ unsigned ld_llc_u16(const unsigned short* p) {
    unsigned r;
    asm volatile("global_load_ushort %0, %1, off sc0 sc1" : "=v"(r) : "v"(p));
    return r;
}
static __device__ __forceinline__ void vwait0() {
    asm volatile("s_waitcnt vmcnt(0)" ::: "memory");
    __builtin_amdgcn_sched_barrier(0);   // rule #18
}

// ---- flag wait/post: line(t,g)=cnt+t*128+g*16 ints; fam dword 0..1 ---------
static __device__ __forceinline__ void wait_fam(const int* cnt, int t, int fam, int quota) {
    const int* b = cnt + t * 128 + fam;
    for (;;) {
        int a0,a1,a2,a3,a4,a5,a6,a7;
        asm volatile("global_load_dword %0, %1, off sc0 sc1" : "=v"(a0) : "v"(b));
        asm volatile("global_load_dword %0, %1, off sc0 sc1" : "=v"(a1) : "v"(b+16));
        asm volatile("global_load_dword %0, %1, off sc0 sc1" : "=v"(a2) : "v"(b+32));
        asm volatile("global_load_dword %0, %1, off sc0 sc1" : "=v"(a3) : "v"(b+48));
        asm volatile("global_load_dword %0, %1, off sc0 sc1" : "=v"(a4) : "v"(b+64));
        asm volatile("global_load_dword %0, %1, off sc0 sc1" : "=v"(a5) : "v"(b+80));
        asm volatile("global_load_dword %0, %1, off sc0 sc1" : "=v"(a6) : "v"(b+96));
        asm volatile("global_load_dword %0, %1, off sc0 sc1" : "=v"(a7) : "v"(b+112));
        asm volatile("s_waitcnt vmcnt(0)" ::: "memory");
        __builtin_amdgcn_sched_barrier(0);
        if (a0>=quota && a1>=quota && a2>=quota && a3>=quota &&
            a4>=quota && a5>=quota && a6>=quota && a7>=quota) break;
        __builtin_amdgcn_s_sleep(1);
    }
}
static __device__ __forceinline__ void wg_wait(const int* cnt, int t, int fam, int quota) {
    if (threadIdx.x == 0) wait_fam(cnt, t, fam, quota);
    __syncthreads();
}
static __device__ __forceinline__ void post_fam(int* cnt, int t, int g, int fam) {
    __hip_atomic_fetch_add(cnt + t * 128 + g * 16 + fam, 1,
                           __ATOMIC_RELAXED, __HIP_MEMORY_SCOPE_AGENT);
}

// ---------------- weight packing (verbatim, verified rounds 1-18) -----------
// Wur: [kk=64][b=128][kg=4][col=16][8] (u cols: b<64, r cols: b>=64)
// Wc : [kk=64][b=64 ][kg=4][col=16][8], K order = [x | h].
__global__ __launch_bounds__(256) void gru_pack_weights(
    const float* __restrict__ wihu, const float* __restrict__ wihr,
    const float* __restrict__ wihc, const float* __restrict__ whhu,
    const float* __restrict__ whhr, const float* __restrict__ whhc,
    unsigned short* __restrict__ Wur, unsigned short* __restrict__ Wc)
{
    const int total = 3072 * 2048;
    for (int idx = blockIdx.x * 256 + threadIdx.x; idx < total; idx += gridDim.x * 256) {
        int n = idx >> 11;
        int k = idx & 2047;
        int j = n & 1023;
        float v;
        if (n < 1024)      v = (k < DIN) ? wihu[j*DIN + k] : whhu[j*DH + (k - DIN)];
        else if (n < 2048) v = (k < DIN) ? wihr[j*DIN + k] : whhr[j*DH + (k - DIN)];
        else               v = (k < DIN) ? wihc[j*DIN + k] : whhc[j*DH + (k - DIN)];
        unsigned short bv = f2bf(v);
        int kk = k >> 5, kg = (k >> 3) & 3, r = k & 7;
        if (n < 2048) {
            int b = n >> 4, col = n & 15;
            Wur[((((size_t)kk*128 + b)*4 + kg)*16 + col)*8 + r] = bv;
        } else {
            int nc = n - 2048, b = nc >> 4, col = nc & 15;
            Wc [((((size_t)kk*64 + b)*4 + kg)*16 + col)*8 + r] = bv;
        }
    }
}

// ---------------- emb fp32 -> bf16 (deep path) ------------------------------
__global__ __launch_bounds__(256) void gru_convert_x(
    const float* __restrict__ emb, unsigned short* __restrict__ xbf)
{
    size_t i = (size_t)blockIdx.x * 256 + threadIdx.x;
    float4 v = ((const float4*)emb)[i];
    ushort4 b;
    b.x = f2bf(v.x); b.y = f2bf(v.y); b.z = f2bf(v.z); b.w = f2bf(v.w);
    ((ushort4*)xbf)[i] = b;
}

// ---------------- init: hA[0] = bf16(h0) frag-packed, counters = 0 ----------
__global__ __launch_bounds__(256) void gru_init(
    const float* __restrict__ hx, unsigned short* __restrict__ hA,
    int* __restrict__ cnt)
{
    int i = blockIdx.x * 256 + threadIdx.x;   // 256x256 = 65536
    int row = i >> 10, k = i & 1023;
    hA[fidx(row, k)] = f2bf(hx[i]);
    cnt[i] = 0;
}

// ---------------- persistent GRU kernel -------------------------------------
// c-WG (wg<64): u-gate + cell + h-update for cols [16wg,16wg+16).
// r-WG (wg>=64): r-gate for cols [16(wg-64),...); publishes rh.
__global__ __launch_bounds__(256, 1) void gru_persistent(
    const unsigned short* __restrict__ Wur, const unsigned short* __restrict__ Wc,
    const float* __restrict__ emb, const unsigned short* __restrict__ xbf,
    const float* __restrict__ hx,
    const float* __restrict__ bu, const float* __restrict__ br, const float* __restrict__ bc,
    unsigned short* __restrict__ hA, unsigned short* __restrict__ rh,
    float* __restrict__ out, int* __restrict__ cnt, int deep)
{
    __shared__ unsigned short wur_s[32768];   // 64 KB: this WG's 16-col u/r slice
    __shared__ unsigned short wc_s [32768];   // 64 KB: c-WGs' 16-col c slice

    const int wg   = blockIdx.x;
    const int tid  = threadIdx.x;
    const int lane = tid & 63;
    const int wid  = tid >> 6;
    const int m0   = wid * 16;
    const int c15  = lane & 15;
    const int kg   = lane >> 4;

    for (int i = tid; i < 4096; i += 256) {
        int kk = i >> 6, j = i & 63;
        *((uint4*)wur_s + i) =
            *(const uint4*)((const char*)Wur + ((size_t)kk*128 + wg)*1024 + j*16);
    }
    if (wg < 64) {
        for (int i = tid; i < 4096; i += 256) {
            int kk = i >> 6, j = i & 63;
            *((uint4*)wc_s + i) =
                *(const uint4*)((const char*)Wc + ((size_t)kk*64 + wg)*1024 + j*16);
        }
    }
    __syncthreads();

    const int v    = wg & 63;
    const int colj = v * 16 + c15;

    if (wg < 64) {
        // ================= c-path: u + cell + h-update =================
        const float bu_ = bu[colj], bc_ = bc[colj];
        float hreg[4];
        #pragma unroll
        for (int i = 0; i < 4; ++i) hreg[i] = hx[(m0 + kg*4 + i) * DH + colj];

        for (int t = 0; t < T_STEPS; ++t) {
            const int par = t & 1;
            const unsigned short* ha   = hA + par * SLAB;
            unsigned short*       hnxt = hA + (par ^ 1) * SLAB;

            f32x4 au = {0.f,0.f,0.f,0.f}, ac = {0.f,0.f,0.f,0.f};
            bf16x8 fr[32];

            // --- x-parts of u and c (cached; overlaps waiting time) ---
            if (deep) {
                const unsigned short* xp =
                    xbf + ((size_t)t * BATCH + (m0 + c15)) * DIN + kg * 8;
                #pragma unroll
                for (int kk = 0; kk < 32; ++kk) {
                    bf16x8 f = *(const bf16x8*)(xp + kk * 32);
                    au = __builtin_amdgcn_mfma_f32_16x16x32_bf16(
                             f, *(const bf16x8*)(wur_s + kk*512 + lane*8), au, 0, 0, 0);
                    ac = __builtin_amdgcn_mfma_f32_16x16x32_bf16(
                             f, *(const bf16x8*)(wc_s + kk*512 + lane*8), ac, 0, 0, 0);
                }
            } else {
                const float* xp = emb + ((size_t)t * BATCH + (m0 + c15)) * DIN + kg * 8;
                #pragma unroll
                for (int kk = 0; kk < 32; ++kk) {
                    float4 a = *(const float4*)(xp + kk * 32);
                    float4 b = *(const float4*)(xp + kk * 32 + 4);
                    bf16x8 f = cvt8(a, b);
                    au = __builtin_amdgcn_mfma_f32_16x16x32_bf16(
                             f, *(const bf16x8*)(wur_s + kk*512 + lane*8), au, 0, 0, 0);
                    ac = __builtin_amdgcn_mfma_f32_16x16x32_bf16(
                             f, *(const bf16x8*)(wc_s + kk*512 + lane*8), ac, 0, 0, 0);
                }
            }

            // --- h-part of u (bypass, frag-linear: 1KB contiguous/instr) ---
            if (t) wg_wait(cnt, t-1, 0, 8);
            const unsigned short* hb = ha + wid * 16384;    // row-block slab
            #pragma unroll
            for (int kk = 0; kk < 32; ++kk) fr[kk] = ld_llc(hb + kk * 512 + lane * 8);
            vwait0();
            #pragma unroll
            for (int kk = 0; kk < 32; ++kk)
                au = __builtin_amdgcn_mfma_f32_16x16x32_bf16(
                         fr[kk], *(const bf16x8*)(wur_s + (kk+32)*512 + lane*8), au, 0, 0, 0);

            // --- single R wait; issue full rh burst; sigmoid hides under it ---
            const unsigned short* rb = rh + wid * 16384;
            wg_wait(cnt, t, 1, 8);
            #pragma unroll
            for (int kk = 0; kk < 32; ++kk) fr[kk] = ld_llc(rb + kk * 512 + lane * 8);

            float ureg[4];
            #pragma unroll
            for (int i = 0; i < 4; ++i)
                ureg[i] = 1.f / (1.f + __expf(-(au[i] + bu_)));

            vwait0();
            #pragma unroll
            for (int kk = 0; kk < 32; ++kk)
                ac = __builtin_amdgcn_mfma_f32_16x16x32_bf16(
                         fr[kk], *(const bf16x8*)(wc_s + (kk+32)*512 + lane*8), ac, 0, 0, 0);

            // --- update, publish h (frag-linear WT), post H; out after ---
            float hnv[4];
            #pragma unroll
            for (int i = 0; i < 4; ++i) {
                int row = m0 + kg * 4 + i;
                float pre = ac[i] + bc_;
                float e   = __expf(2.f * pre);
                float cel = 1.f - 2.f / (e + 1.f);          // tanh
                float hn  = (1.f - ureg[i]) * hreg[i] + ureg[i] * cel;
                hreg[i] = hn;
                hnv[i]  = hn;
                st_wt_u16(hnxt + fidx(row, colj), (unsigned)f2bf(hn));
            }
            asm volatile("s_waitcnt vmcnt(0)" ::: "memory");
            __syncthreads();
            if (tid == 0) post_fam(cnt, t, wg >> 3, 0);

            float* out_t = out + (size_t)t * SLAB;          // write-only, off-path
            #pragma unroll
            for (int i = 0; i < 4; ++i) {
                int row = m0 + kg * 4 + i;
                out_t[row * DH + colj] = hnv[i];
                if (t == T_STEPS - 1)
                    out[(size_t)T_STEPS * SLAB + row * DH + colj] = hnv[i];
            }
        }
    } else {
        // ================= r-path: reset gate -> rh =================
        const float br_ = br[colj];
        for (int t = 0; t < T_STEPS; ++t) {
            const int par = t & 1;
            const unsigned short* ha = hA + par * SLAB;

            f32x4 ar = {0.f,0.f,0.f,0.f};
            bf16x8 fr[32];

            // --- x-part of r (cached; overlaps waiting time) ---
            if (deep) {
                const unsigned short* xp =
                    xbf + ((size_t)t * BATCH + (m0 + c15)) * DIN + kg * 8;
                #pragma unroll
                for (int kk = 0; kk < 32; ++kk)
                    ar = __builtin_amdgcn_mfma_f32_16x16x32_bf16(
                             *(const bf16x8*)(xp + kk * 32),
                             *(const bf16x8*)(wur_s + kk*512 + lane*8), ar, 0, 0, 0);
            } else {
                const float* xp = emb + ((size_t)t * BATCH + (m0 + c15)) * DIN + kg * 8;
                #pragma unroll
                for (int kk = 0; kk < 32; ++kk) {
                    float4 a = *(const float4*)(xp + kk * 32);
                    float4 b = *(const float4*)(xp + kk * 32 + 4);
                    ar = __builtin_amdgcn_mfma_f32_16x16x32_bf16(
                             cvt8(a, b), *(const bf16x8*)(wur_s + kk*512 + lane*8),
                             ar, 0, 0, 0);
                }
            }

            // --- h-part of r (frag-linear bypass; + own-col h scalars) ---
            if (t) wg_wait(cnt, t-1, 0, 8);
            const unsigned short* hb = ha + wid * 16384;
            unsigned hp16[4];
            #pragma unroll
            for (int i = 0; i < 4; ++i)
                hp16[i] = ld_llc_u16(ha + fidx(m0 + kg*4 + i, colj));
            #pragma unroll
            for (int kk = 0; kk < 32; ++kk) fr[kk] = ld_llc(hb + kk * 512 + lane * 8);
            vwait0();
            #pragma unroll
            for (int kk = 0; kk < 32; ++kk)
                ar = __builtin_amdgcn_mfma_f32_16x16x32_bf16(
                         fr[kk], *(const bf16x8*)(wur_s + (kk+32)*512 + lane*8),
                         ar, 0, 0, 0);

            // --- publish rh (frag-linear WT), post R (single family q8) ---
            #pragma unroll
            for (int i = 0; i < 4; ++i) {
                int row = m0 + kg * 4 + i;
                float s = 1.f / (1.f + __expf(-(ar[i] + br_)));
                st_wt_u16(rh + fidx(row, colj),
                          (unsigned)f2bf(s * bf2f((unsigned short)hp16[i])));
            }
            asm volatile("s_waitcnt vmcnt(0)" ::: "memory");
            __syncthreads();
            if (tid == 0) post_fam(cnt, t, v >> 3, 1);
        }
    }
}

// ---------------- host launch ----------------------------------------------
extern "C" void kernel_launch(void* const* d_in, const int* in_sizes, int n_in,
                              void* d_out, int out_size, void* d_ws, size_t ws_size,
                              hipStream_t stream)
{
    const float* emb  = (const float*)d_in[0];
    const float* hx   = (const float*)d_in[1];
    const float* wihu = (const float*)d_in[2];
    const float* wihr = (const float*)d_in[3];
    const float* wihc = (const float*)d_in[4];
    const float* whhu = (const float*)d_in[5];
    const float* whhr = (const float*)d_in[6];
    const float* whhc = (const float*)d_in[7];
    const float* bu   = (const float*)d_in[8];
    const float* br   = (const float*)d_in[9];
    const float* bc   = (const float*)d_in[10];
    float* out = (float*)d_out;
    char*  ws  = (char*)d_ws;

    // ws layout (bytes) — identical to R11/R15/R18:
    unsigned short* Wur = (unsigned short*)(ws + 0);          // 8 MiB
    unsigned short* Wc  = (unsigned short*)(ws + 8388608);    // 4 MiB
    int*            cnt = (int*)(ws + 12582912);              // 256 KiB flag lines
    unsigned short* hA  = (unsigned short*)(ws + 12845056);   // 256 KiB (2 slabs)
    unsigned short* rhb = (unsigned short*)(ws + 13107200);   // 128 KiB
    unsigned short* xbf = (unsigned short*)(ws + 16777216);   // 64 MiB (deep)
    const int deep = (ws_size >= 83886080ull) ? 1 : 0;

    gru_pack_weights<<<1024, 256, 0, stream>>>(wihu, wihr, wihc, whhu, whhr, whhc, Wur, Wc);
    if (deep) gru_convert_x<<<32768, 256, 0, stream>>>(emb, xbf);
    gru_init<<<256, 256, 0, stream>>>(hx, hA, cnt);
    gru_persistent<<<NWG, 256, 0, stream>>>(Wur, Wc, emb, xbf, hx, bu, br, bc,
                                            hA, rhb, out, cnt, deep);
}